// Round 1
// baseline (716.784 us; speedup 1.0000x reference)
//
#include <hip/hip_runtime.h>
#include <hip/hip_bf16.h>

#define IN_CHN 256
#define OUT_CHN 256
#define REL_DIM 1536
#define HIDN 512

using short8 = __attribute__((ext_vector_type(8))) short;
using f32x4  = __attribute__((ext_vector_type(4))) float;

__device__ __forceinline__ float bf2f(short s) {
    union { unsigned u; float f; } v;
    v.u = ((unsigned)(unsigned short)s) << 16;
    return v.f;
}
// packed f32->bf16 (RNE) — schedulable (non-volatile) inline asm
__device__ __forceinline__ unsigned cvt_pk_bf16(float a, float b) {
    unsigned r;
    asm("v_cvt_pk_bf16_f32 %0, %1, %2" : "=v"(r) : "v"(a), "v"(b));
    return r;
}
__device__ __forceinline__ unsigned short f2bf_s(float f) {
    union { float f; unsigned u; } v; v.f = f;
    unsigned u = v.u + 0x7FFFu + ((v.u >> 16) & 1u);
    return (unsigned short)(u >> 16);
}

// ---------------- prep: transpose+cast weights to bf16 ----------------
// Bt [768][256]  : cols 0..511 = W1_top^T, cols 512..767 = Ws^T
// W2t[256][512]  : W2^T
__global__ void k_prep_w(const float* __restrict__ W1, const float* __restrict__ Ws,
                         const float* __restrict__ W2,
                         unsigned short* __restrict__ Bt, unsigned short* __restrict__ W2t)
{
    int idx = blockIdx.x * 256 + threadIdx.x;
    const int nBt = 768 * IN_CHN;
    if (idx < nBt) {
        int j = idx >> 8, k = idx & 255;
        float v = (j < HIDN) ? W1[(size_t)k * HIDN + j] : Ws[(size_t)k * OUT_CHN + (j - HIDN)];
        Bt[idx] = f2bf_s(v);
    } else {
        int t = idx - nBt;
        if (t < OUT_CHN * HIDN) {
            int j = t >> 9, k = t & 511;
            W2t[t] = f2bf_s(W2[(size_t)k * OUT_CHN + j]);
        }
    }
}

// ---------------- R[r] = rel[r] @ W1_bot + b1 (bf16 out) ----------------
__global__ __launch_bounds__(512) void k_rel(const float* __restrict__ rel,
                                             const float* __restrict__ W1,
                                             const float* __restrict__ b1,
                                             unsigned short* __restrict__ Rb)
{
    __shared__ float s[REL_DIM];
    const int r = blockIdx.x;
    for (int i = threadIdx.x; i < REL_DIM; i += 512)
        s[i] = rel[(size_t)r * REL_DIM + i];
    __syncthreads();
    const int j = threadIdx.x;
    float acc = b1[j];
    const float* wp = W1 + (size_t)IN_CHN * HIDN + j;
#pragma unroll 8
    for (int k = 0; k < REL_DIM; ++k)
        acc = fmaf(s[k], wp[(size_t)k * HIDN], acc);
    Rb[r * HIDN + j] = f2bf_s(acc);
}

// ---------------- node GEMM: [X1 | out] = bf16(x) @ Bt^T ----------------
// grid (ceil(N/64), 3); block 256. Block covers 64 rows x 256 cols.
__global__ __launch_bounds__(256) void k_node(const float* __restrict__ x,
                                              const unsigned short* __restrict__ Bt,
                                              const float* __restrict__ bs,
                                              unsigned short* __restrict__ X1,
                                              float* __restrict__ out, int N)
{
    const int row0 = blockIdx.x * 64;
    const int colb = blockIdx.y * 256;
    const int tid = threadIdx.x;
    const int w = tid >> 6, l = tid & 63;
    const int l15 = l & 15, lg = l >> 4;
    const int colw = colb + w * 64;

    const float* ap[4];
#pragma unroll
    for (int rf = 0; rf < 4; ++rf) {
        int row = row0 + 16 * rf + l15;
        if (row >= N) row = N - 1;              // clamp; stores predicated below
        ap[rf] = x + (size_t)row * IN_CHN + 8 * lg;
    }
    const unsigned short* bp[4];
#pragma unroll
    for (int cf = 0; cf < 4; ++cf)
        bp[cf] = Bt + (size_t)(colw + 16 * cf + l15) * IN_CHN + 8 * lg;

    f32x4 acc[4][4] = {};
    for (int k0 = 0; k0 < IN_CHN; k0 += 32) {
        short8 a[4], b[4];
#pragma unroll
        for (int rf = 0; rf < 4; ++rf) {
            float4 lo = *(const float4*)(ap[rf] + k0);
            float4 hi = *(const float4*)(ap[rf] + k0 + 4);
            union { short8 s; unsigned u[4]; } pk;
            pk.u[0] = cvt_pk_bf16(lo.x, lo.y);
            pk.u[1] = cvt_pk_bf16(lo.z, lo.w);
            pk.u[2] = cvt_pk_bf16(hi.x, hi.y);
            pk.u[3] = cvt_pk_bf16(hi.z, hi.w);
            a[rf] = pk.s;
        }
#pragma unroll
        for (int cf = 0; cf < 4; ++cf)
            b[cf] = *(const short8*)(bp[cf] + k0);
#pragma unroll
        for (int rf = 0; rf < 4; ++rf)
#pragma unroll
            for (int cf = 0; cf < 4; ++cf)
                acc[rf][cf] = __builtin_amdgcn_mfma_f32_16x16x32_bf16(a[rf], b[cf], acc[rf][cf], 0, 0, 0);
    }
#pragma unroll
    for (int rf = 0; rf < 4; ++rf) {
#pragma unroll
        for (int cf = 0; cf < 4; ++cf) {
            int col = colw + 16 * cf + l15;
#pragma unroll
            for (int r = 0; r < 4; ++r) {
                int row = row0 + 16 * rf + 4 * lg + r;
                if (row >= N) continue;
                float v = acc[rf][cf][r];
                if (col < HIDN) {
                    X1[(size_t)row * HIDN + col] = f2bf_s(v);
                } else {
                    out[(size_t)row * OUT_CHN + (col - HIDN)] = v + bs[col - HIDN];
                }
            }
        }
    }
}

// ---------------- edge kernel: msg = relu(X1[src]+R[et]) @ W2t, atomic scatter ----------------
// grid ceil(E/64); block 256 (4 waves). Block = 64 edges x 256 cols, K=512.
__global__ __launch_bounds__(256) void k_edge(const int* __restrict__ ei,
                                              const int* __restrict__ etype,
                                              const unsigned short* __restrict__ X1,
                                              const unsigned short* __restrict__ Rb,
                                              const unsigned short* __restrict__ W2t,
                                              const float* __restrict__ b2,
                                              float* __restrict__ out, int E)
{
    __shared__ unsigned short sh[2][64 * 32];   // h tile, double-buffered, chunk-rotated
    __shared__ int s_dst[64];
    const int e0 = blockIdx.x * 64;
    const int tid = threadIdx.x;

    int esrc = 0, eet = 0;
    {
        int eL = e0 + (tid >> 2);
        if (eL < E) { esrc = ei[eL]; eet = etype[eL]; }
        if (tid < 64) {
            int e = e0 + tid;
            s_dst[tid] = (e < E) ? ei[E + e] : -1;
        }
    }
    __syncthreads();

    // staging role: thread t handles edge t>>2, k-chunk (t&3)*8
    const int srow = tid >> 2;
    const int skc = tid & 3;
    const unsigned short* xs = X1 + (size_t)esrc * HIDN + skc * 8;
    const unsigned short* rs = Rb + (size_t)eet * HIDN + skc * 8;
    const int swc = skc ^ ((srow >> 1) & 3);    // bank-aliasing rotation
    const int swoff = srow * 32 + swc * 8;

    const int w = tid >> 6, l = tid & 63;
    const int l15 = l & 15, lg = l >> 4;
    const unsigned short* bp[4];
#pragma unroll
    for (int cf = 0; cf < 4; ++cf)
        bp[cf] = W2t + (size_t)(w * 64 + 16 * cf + l15) * HIDN + 8 * lg;
    int ard[4];
#pragma unroll
    for (int rf = 0; rf < 4; ++rf) {
        int arow = 16 * rf + l15;
        int ac = lg ^ ((arow >> 1) & 3);
        ard[rf] = arow * 32 + ac * 8;
    }

    f32x4 acc[4][4] = {};
    for (int kk = 0; kk < 16; ++kk) {
        const int k0 = kk * 32;
        // stage h chunk (all 256 threads; amortized over all 4 waves)
        short8 xa = *(const short8*)(xs + k0);
        short8 ra = *(const short8*)(rs + k0);
        float f[8];
#pragma unroll
        for (int i = 0; i < 8; ++i)
            f[i] = fmaxf(bf2f(xa[i]) + bf2f(ra[i]), 0.f);
        union { short8 s; unsigned u[4]; } pk;
        pk.u[0] = cvt_pk_bf16(f[0], f[1]);
        pk.u[1] = cvt_pk_bf16(f[2], f[3]);
        pk.u[2] = cvt_pk_bf16(f[4], f[5]);
        pk.u[3] = cvt_pk_bf16(f[6], f[7]);
        unsigned short* sw = &sh[kk & 1][swoff];
        *(short8*)sw = pk.s;
        __syncthreads();
        const unsigned short* base = sh[kk & 1];
        short8 a[4], b[4];
#pragma unroll
        for (int rf = 0; rf < 4; ++rf)
            a[rf] = *(const short8*)(base + ard[rf]);
#pragma unroll
        for (int cf = 0; cf < 4; ++cf)
            b[cf] = *(const short8*)(bp[cf] + k0);
#pragma unroll
        for (int rf = 0; rf < 4; ++rf)
#pragma unroll
            for (int cf = 0; cf < 4; ++cf)
                acc[rf][cf] = __builtin_amdgcn_mfma_f32_16x16x32_bf16(a[rf], b[cf], acc[rf][cf], 0, 0, 0);
    }

    float b2v[4];
#pragma unroll
    for (int cf = 0; cf < 4; ++cf) b2v[cf] = b2[w * 64 + 16 * cf + l15];
#pragma unroll
    for (int rf = 0; rf < 4; ++rf) {
#pragma unroll
        for (int r = 0; r < 4; ++r) {
            int el = 16 * rf + 4 * lg + r;
            int dst = s_dst[el];
            if (dst < 0) continue;
            float* op = out + (size_t)dst * OUT_CHN;
#pragma unroll
            for (int cf = 0; cf < 4; ++cf) {
                int col = w * 64 + 16 * cf + l15;
                atomicAdd(op + col, acc[rf][cf][r] + b2v[cf]);
            }
        }
    }
}

// ---------------- in-place LayerNorm + ReLU ----------------
__global__ __launch_bounds__(256) void k_ln(float* __restrict__ out,
                                            const float* __restrict__ gamma,
                                            const float* __restrict__ beta, int N)
{
    const int w = threadIdx.x >> 6, l = threadIdx.x & 63;
    const long row = (long)blockIdx.x * 4 + w;
    if (row >= N) return;
    float* p = out + row * OUT_CHN + l * 4;
    float4 v = *(const float4*)p;
    float s = v.x + v.y + v.z + v.w;
    float s2 = v.x * v.x + v.y * v.y + v.z * v.z + v.w * v.w;
#pragma unroll
    for (int o = 32; o > 0; o >>= 1) {
        s  += __shfl_xor(s, o);
        s2 += __shfl_xor(s2, o);
    }
    const float inv = 1.0f / OUT_CHN;
    float mu = s * inv;
    float var = s2 * inv - mu * mu;
    float rstd = rsqrtf(var + 1e-5f);
    float4 g = *(const float4*)(gamma + l * 4);
    float4 b = *(const float4*)(beta + l * 4);
    v.x = fmaxf((v.x - mu) * rstd * g.x + b.x, 0.f);
    v.y = fmaxf((v.y - mu) * rstd * g.y + b.y, 0.f);
    v.z = fmaxf((v.z - mu) * rstd * g.z + b.z, 0.f);
    v.w = fmaxf((v.w - mu) * rstd * g.w + b.w, 0.f);
    *(float4*)p = v;
}

extern "C" void kernel_launch(void* const* d_in, const int* in_sizes, int n_in,
                              void* d_out, int out_size, void* d_ws, size_t ws_size,
                              hipStream_t stream)
{
    const float* x     = (const float*)d_in[0];
    const int*   ei    = (const int*)d_in[1];
    const int*   etype = (const int*)d_in[2];
    const float* rel   = (const float*)d_in[3];
    const float* W1    = (const float*)d_in[4];
    const float* b1    = (const float*)d_in[5];
    const float* W2    = (const float*)d_in[6];
    const float* b2    = (const float*)d_in[7];
    const float* Ws    = (const float*)d_in[8];
    const float* bs    = (const float*)d_in[9];
    const float* gamma = (const float*)d_in[10];
    const float* beta  = (const float*)d_in[11];

    const int N  = in_sizes[0] / IN_CHN;
    const int E  = in_sizes[2];
    const int NR = in_sizes[3] / REL_DIM;
    float* outp = (float*)d_out;

    // workspace carve (~103 MB)
    char* wsp = (char*)d_ws;
    auto carve = [&](size_t bytes) { char* p = wsp; wsp += (bytes + 255) & ~(size_t)255; return p; };
    unsigned short* X1  = (unsigned short*)carve((size_t)N * HIDN * 2);
    unsigned short* Rb  = (unsigned short*)carve((size_t)NR * HIDN * 2);
    unsigned short* Bt  = (unsigned short*)carve((size_t)768 * IN_CHN * 2);
    unsigned short* W2t = (unsigned short*)carve((size_t)OUT_CHN * HIDN * 2);

    const int prep_total = 768 * IN_CHN + OUT_CHN * HIDN;
    k_prep_w<<<dim3((prep_total + 255) / 256), dim3(256), 0, stream>>>(W1, Ws, W2, Bt, W2t);
    k_rel<<<dim3(NR), dim3(512), 0, stream>>>(rel, W1, b1, Rb);
    k_node<<<dim3((N + 63) / 64, 3), dim3(256), 0, stream>>>(x, Bt, bs, X1, outp, N);
    k_edge<<<dim3((E + 63) / 64), dim3(256), 0, stream>>>(ei, etype, X1, Rb, W2t, b2, outp, E);
    k_ln<<<dim3((N + 3) / 4), dim3(256), 0, stream>>>(outp, gamma, beta, N);
}

// Round 2
// 612.818 us; speedup vs baseline: 1.1697x; 1.1697x over previous
//
#include <hip/hip_runtime.h>
#include <hip/hip_bf16.h>

#define IN_CHN 256
#define OUT_CHN 256
#define REL_DIM 1536
#define HIDN 512

using short8 = __attribute__((ext_vector_type(8))) short;
using f32x4  = __attribute__((ext_vector_type(4))) float;

__device__ __forceinline__ float bf2f(short s) {
    union { unsigned u; float f; } v;
    v.u = ((unsigned)(unsigned short)s) << 16;
    return v.f;
}
__device__ __forceinline__ unsigned cvt_pk_bf16(float a, float b) {
    unsigned r;
    asm("v_cvt_pk_bf16_f32 %0, %1, %2" : "=v"(r) : "v"(a), "v"(b));
    return r;
}
__device__ __forceinline__ unsigned short f2bf_s(float f) {
    union { float f; unsigned u; } v; v.f = f;
    unsigned u = v.u + 0x7FFFu + ((v.u >> 16) & 1u);
    return (unsigned short)(u >> 16);
}

// ---------------- prep: transpose+cast weights to bf16 ----------------
// Bt [768][256]  : cols 0..511 = W1_top^T, cols 512..767 = Ws^T
// W2t[256][512]  : W2^T
__global__ void k_prep_w(const float* __restrict__ W1, const float* __restrict__ Ws,
                         const float* __restrict__ W2,
                         unsigned short* __restrict__ Bt, unsigned short* __restrict__ W2t)
{
    int idx = blockIdx.x * 256 + threadIdx.x;
    const int nBt = 768 * IN_CHN;
    if (idx < nBt) {
        int j = idx >> 8, k = idx & 255;
        float v = (j < HIDN) ? W1[(size_t)k * HIDN + j] : Ws[(size_t)k * OUT_CHN + (j - HIDN)];
        Bt[idx] = f2bf_s(v);
    } else {
        int t = idx - nBt;
        if (t < OUT_CHN * HIDN) {
            int j = t >> 9, k = t & 511;
            W2t[t] = f2bf_s(W2[(size_t)k * OUT_CHN + j]);
        }
    }
}

// ---------------- x -> bf16 precast ----------------
__global__ void k_prep_x(const float* __restrict__ x, unsigned short* __restrict__ xb, long total8)
{
    long i = (long)blockIdx.x * 256 + threadIdx.x;
    if (i >= total8) return;
    const float* p = x + i * 8;
    float4 lo = *(const float4*)p, hi = *(const float4*)(p + 4);
    union { short8 s; unsigned u[4]; } pk;
    pk.u[0] = cvt_pk_bf16(lo.x, lo.y);
    pk.u[1] = cvt_pk_bf16(lo.z, lo.w);
    pk.u[2] = cvt_pk_bf16(hi.x, hi.y);
    pk.u[3] = cvt_pk_bf16(hi.z, hi.w);
    *(short8*)(xb + i * 8) = pk.s;
}

// ---------------- R[r] = rel[r] @ W1_bot + b1 (bf16 out) ----------------
__global__ __launch_bounds__(512) void k_rel(const float* __restrict__ rel,
                                             const float* __restrict__ W1,
                                             const float* __restrict__ b1,
                                             unsigned short* __restrict__ Rb)
{
    __shared__ float s[REL_DIM];
    const int r = blockIdx.x;
    for (int i = threadIdx.x; i < REL_DIM; i += 512)
        s[i] = rel[(size_t)r * REL_DIM + i];
    __syncthreads();
    const int j = threadIdx.x;
    float acc = b1[j];
    const float* wp = W1 + (size_t)IN_CHN * HIDN + j;
#pragma unroll 8
    for (int k = 0; k < REL_DIM; ++k)
        acc = fmaf(s[k], wp[(size_t)k * HIDN], acc);
    Rb[r * HIDN + j] = f2bf_s(acc);
}

// ---------------- node GEMM: [X1 | out] = bf16(x) @ Bt^T ----------------
template<bool XB>
__global__ __launch_bounds__(256) void k_node(const float* __restrict__ x,
                                              const unsigned short* __restrict__ xb,
                                              const unsigned short* __restrict__ Bt,
                                              const float* __restrict__ bs,
                                              unsigned short* __restrict__ X1,
                                              float* __restrict__ out, int N)
{
    const int row0 = blockIdx.x * 64;
    const int colb = blockIdx.y * 256;
    const int tid = threadIdx.x;
    const int w = tid >> 6, l = tid & 63;
    const int l15 = l & 15, lg = l >> 4;
    const int colw = colb + w * 64;

    const float* ap[4];
    const unsigned short* abp[4];
#pragma unroll
    for (int rf = 0; rf < 4; ++rf) {
        int row = row0 + 16 * rf + l15;
        if (row >= N) row = N - 1;              // clamp; stores predicated below
        if constexpr (XB) abp[rf] = xb + (size_t)row * IN_CHN + 8 * lg;
        else              ap[rf]  = x  + (size_t)row * IN_CHN + 8 * lg;
    }
    const unsigned short* bp[4];
#pragma unroll
    for (int cf = 0; cf < 4; ++cf)
        bp[cf] = Bt + (size_t)(colw + 16 * cf + l15) * IN_CHN + 8 * lg;

    f32x4 acc[4][4] = {};
    for (int k0 = 0; k0 < IN_CHN; k0 += 32) {
        short8 a[4], b[4];
#pragma unroll
        for (int rf = 0; rf < 4; ++rf) {
            if constexpr (XB) {
                a[rf] = *(const short8*)(abp[rf] + k0);
            } else {
                float4 lo = *(const float4*)(ap[rf] + k0);
                float4 hi = *(const float4*)(ap[rf] + k0 + 4);
                union { short8 s; unsigned u[4]; } pk;
                pk.u[0] = cvt_pk_bf16(lo.x, lo.y);
                pk.u[1] = cvt_pk_bf16(lo.z, lo.w);
                pk.u[2] = cvt_pk_bf16(hi.x, hi.y);
                pk.u[3] = cvt_pk_bf16(hi.z, hi.w);
                a[rf] = pk.s;
            }
        }
#pragma unroll
        for (int cf = 0; cf < 4; ++cf)
            b[cf] = *(const short8*)(bp[cf] + k0);
#pragma unroll
        for (int rf = 0; rf < 4; ++rf)
#pragma unroll
            for (int cf = 0; cf < 4; ++cf)
                acc[rf][cf] = __builtin_amdgcn_mfma_f32_16x16x32_bf16(a[rf], b[cf], acc[rf][cf], 0, 0, 0);
    }
#pragma unroll
    for (int rf = 0; rf < 4; ++rf) {
#pragma unroll
        for (int cf = 0; cf < 4; ++cf) {
            int col = colw + 16 * cf + l15;
#pragma unroll
            for (int r = 0; r < 4; ++r) {
                int row = row0 + 16 * rf + 4 * lg + r;
                if (row >= N) continue;
                float v = acc[rf][cf][r];
                if (col < HIDN) {
                    X1[(size_t)row * HIDN + col] = f2bf_s(v);
                } else {
                    out[(size_t)row * OUT_CHN + (col - HIDN)] = v + bs[col - HIDN];
                }
            }
        }
    }
}

// ---------------- CSR build ----------------
__global__ void k_hist(const int* __restrict__ ei, int* __restrict__ cnt, int E)
{
    int e = blockIdx.x * 256 + threadIdx.x;
    if (e < E) atomicAdd(&cnt[ei[E + e]], 1);
}

__global__ __launch_bounds__(512) void k_scan1(const int* __restrict__ cnt, int* __restrict__ offs,
                                               int* __restrict__ bsum, int N)
{
    __shared__ int s[512];
    int t = threadIdx.x;
    int i = blockIdx.x * 512 + t;
    int v = (i < N) ? cnt[i] : 0;
    s[t] = v;
    __syncthreads();
    for (int d = 1; d < 512; d <<= 1) {
        int a = (t >= d) ? s[t - d] : 0;
        __syncthreads();
        s[t] += a;
        __syncthreads();
    }
    if (i < N) offs[i] = s[t] - v;   // exclusive within block
    if (t == 511) bsum[blockIdx.x] = s[511];
}

__global__ __launch_bounds__(512) void k_scan2(int* __restrict__ bsum, int NB)
{
    __shared__ int s[512];
    int t = threadIdx.x;
    if (t < NB) s[t] = bsum[t];
    __syncthreads();
    if (t == 0) {
        int run = 0;
        for (int j = 0; j < NB; ++j) { int v = s[j]; s[j] = run; run += v; }
    }
    __syncthreads();
    if (t < NB) bsum[t] = s[t];
}

__global__ void k_scan3(int* __restrict__ offs, const int* __restrict__ bsum,
                        int* __restrict__ cursor, int N, int E)
{
    int i = blockIdx.x * 256 + threadIdx.x;
    if (i < N) {
        int v = offs[i] + bsum[i >> 9];
        offs[i] = v;
        cursor[i] = v;
    }
    if (i == 0) offs[N] = E;
}

__global__ void k_scatter(const int* __restrict__ ei, const int* __restrict__ et,
                          int* __restrict__ cursor, int* __restrict__ eperm, int E)
{
    int e = blockIdx.x * 256 + threadIdx.x;
    if (e < E) {
        int d = ei[E + e];
        int pos = atomicAdd(&cursor[d], 1);
        eperm[pos] = ei[e] | (et[e] << 20);   // src | etype<<20 (src<2^17, et<64)
    }
}

// ---------------- fused: gather-aggregate H into LDS, GEMM @W2, +skip, LN, ReLU ----------------
// grid ceil(N/64); block 256 (4 waves). Block owns 64 node rows x all 256 out cols.
__global__ __launch_bounds__(256) void k_agg(const int* __restrict__ offs,
                                             const int* __restrict__ eperm,
                                             const unsigned short* __restrict__ X1,
                                             const unsigned short* __restrict__ Rb,
                                             const unsigned short* __restrict__ W2t,
                                             const float* __restrict__ b2,
                                             const float* __restrict__ gamma,
                                             const float* __restrict__ beta,
                                             float* __restrict__ out, int N)
{
    __shared__ unsigned short shH[64 * HIDN];   // XOR-swizzled (chunk-of-8 ^ (row&7))
    __shared__ float sred[4][64], sqred[4][64];
    __shared__ int sdeg[64];
    const int tid = threadIdx.x;
    const int w = tid >> 6, l = tid & 63;
    const int l15 = l & 15, lg = l >> 4;
    const int row0 = blockIdx.x * 64;

    // ---- phase 1: per-node aggregate relu(X1[src]+R[et]) -> shH ----
    for (int i = 0; i < 16; ++i) {
        int n = w * 16 + i;
        int g = row0 + n;
        int o0 = 0, o1 = 0;
        if (g < N) { o0 = offs[g]; o1 = offs[g + 1]; }
        if (l == 0) sdeg[n] = o1 - o0;
        float a8[8] = {0.f, 0.f, 0.f, 0.f, 0.f, 0.f, 0.f, 0.f};
        for (int o = o0; o < o1; ++o) {
            int pk = eperm[o];
            int src = pk & 0xFFFFF;
            int et = pk >> 20;
            short8 xa = *(const short8*)(X1 + (size_t)src * HIDN + l * 8);
            short8 ra = *(const short8*)(Rb + et * HIDN + l * 8);
#pragma unroll
            for (int j = 0; j < 8; ++j)
                a8[j] += fmaxf(bf2f(xa[j]) + bf2f(ra[j]), 0.f);
        }
        union { short8 s; unsigned u[4]; } pkk;
        pkk.u[0] = cvt_pk_bf16(a8[0], a8[1]);
        pkk.u[1] = cvt_pk_bf16(a8[2], a8[3]);
        pkk.u[2] = cvt_pk_bf16(a8[4], a8[5]);
        pkk.u[3] = cvt_pk_bf16(a8[6], a8[7]);
        *(short8*)(shH + n * HIDN + ((l * 8) ^ ((n & 7) << 3))) = pkk.s;
    }
    __syncthreads();

    // ---- phase 2: GEMM 64x256 (K=512), A from LDS, B = W2t from global ----
    const int colw = w * 64;
    const unsigned short* bp[4];
#pragma unroll
    for (int cf = 0; cf < 4; ++cf)
        bp[cf] = W2t + (size_t)(colw + 16 * cf + l15) * HIDN + 8 * lg;
    int arow[4], axor[4];
#pragma unroll
    for (int rf = 0; rf < 4; ++rf) {
        int rr = 16 * rf + l15;
        arow[rf] = rr * HIDN;
        axor[rf] = (rr & 7) << 3;
    }
    f32x4 acc[4][4] = {};
    for (int k0 = 0; k0 < HIDN; k0 += 32) {
        short8 a[4], b[4];
#pragma unroll
        for (int rf = 0; rf < 4; ++rf)
            a[rf] = *(const short8*)(shH + arow[rf] + ((k0 + 8 * lg) ^ axor[rf]));
#pragma unroll
        for (int cf = 0; cf < 4; ++cf)
            b[cf] = *(const short8*)(bp[cf] + k0);
#pragma unroll
        for (int rf = 0; rf < 4; ++rf)
#pragma unroll
            for (int cf = 0; cf < 4; ++cf)
                acc[rf][cf] = __builtin_amdgcn_mfma_f32_16x16x32_bf16(a[rf], b[cf], acc[rf][cf], 0, 0, 0);
    }

    // ---- epilogue: + out_prev + deg*b2, LayerNorm over 256 cols, ReLU ----
    float b2v[4], gv[4], bv[4];
#pragma unroll
    for (int cf = 0; cf < 4; ++cf) {
        int col = colw + 16 * cf + l15;
        b2v[cf] = b2[col]; gv[cf] = gamma[col]; bv[cf] = beta[col];
    }
#pragma unroll
    for (int rf = 0; rf < 4; ++rf) {
#pragma unroll
        for (int r = 0; r < 4; ++r) {
            int row = 16 * rf + 4 * lg + r;
            int g = row0 + row;
            float dg = (float)sdeg[row];
            float s = 0.f, sq = 0.f;
#pragma unroll
            for (int cf = 0; cf < 4; ++cf) {
                int col = colw + 16 * cf + l15;
                float v = acc[rf][cf][r] + dg * b2v[cf];
                if (g < N) v += out[(size_t)g * OUT_CHN + col];
                acc[rf][cf][r] = v;
                s += v; sq += v * v;
            }
#pragma unroll
            for (int o = 8; o > 0; o >>= 1) {
                s  += __shfl_xor(s, o);
                sq += __shfl_xor(sq, o);
            }
            if (l15 == 0) { sred[w][row] = s; sqred[w][row] = sq; }
        }
    }
    __syncthreads();
#pragma unroll
    for (int rf = 0; rf < 4; ++rf) {
#pragma unroll
        for (int r = 0; r < 4; ++r) {
            int row = 16 * rf + 4 * lg + r;
            int g = row0 + row;
            if (g >= N) continue;
            float tot  = sred[0][row] + sred[1][row] + sred[2][row] + sred[3][row];
            float totq = sqred[0][row] + sqred[1][row] + sqred[2][row] + sqred[3][row];
            float mu = tot * (1.f / OUT_CHN);
            float var = totq * (1.f / OUT_CHN) - mu * mu;
            float rstd = rsqrtf(var + 1e-5f);
#pragma unroll
            for (int cf = 0; cf < 4; ++cf) {
                int col = colw + 16 * cf + l15;
                float v = (acc[rf][cf][r] - mu) * rstd * gv[cf] + bv[cf];
                out[(size_t)g * OUT_CHN + col] = fmaxf(v, 0.f);
            }
        }
    }
}

extern "C" void kernel_launch(void* const* d_in, const int* in_sizes, int n_in,
                              void* d_out, int out_size, void* d_ws, size_t ws_size,
                              hipStream_t stream)
{
    const float* x     = (const float*)d_in[0];
    const int*   ei    = (const int*)d_in[1];
    const int*   etype = (const int*)d_in[2];
    const float* rel   = (const float*)d_in[3];
    const float* W1    = (const float*)d_in[4];
    const float* b1    = (const float*)d_in[5];
    const float* W2    = (const float*)d_in[6];
    const float* b2    = (const float*)d_in[7];
    const float* Ws    = (const float*)d_in[8];
    const float* bs    = (const float*)d_in[9];
    const float* gamma = (const float*)d_in[10];
    const float* beta  = (const float*)d_in[11];

    const int N  = in_sizes[0] / IN_CHN;
    const int E  = in_sizes[2];
    const int NR = in_sizes[3] / REL_DIM;
    float* outp = (float*)d_out;

    char* wsp = (char*)d_ws;
    char* wend = wsp + ws_size;
    auto carve = [&](size_t bytes) { char* p = wsp; wsp += (bytes + 255) & ~(size_t)255; return p; };
    unsigned short* X1  = (unsigned short*)carve((size_t)N * HIDN * 2);
    unsigned short* Rb  = (unsigned short*)carve((size_t)NR * HIDN * 2);
    unsigned short* Bt  = (unsigned short*)carve((size_t)768 * IN_CHN * 2);
    unsigned short* W2t = (unsigned short*)carve((size_t)OUT_CHN * HIDN * 2);
    int* offs  = (int*)carve(((size_t)N + 1) * 4);
    int* cnt   = (int*)carve((size_t)N * 4);        // doubles as scatter cursor
    int* bsum  = (int*)carve(512 * 4);
    int* eperm = (int*)carve((size_t)E * 4);
    size_t xb_bytes = (size_t)N * IN_CHN * 2;
    bool use_xb = ((size_t)(wend - wsp) >= xb_bytes + 512);
    unsigned short* xb = use_xb ? (unsigned short*)carve(xb_bytes) : nullptr;

    hipMemsetAsync(cnt, 0, (size_t)N * 4, stream);

    const int prep_total = 768 * IN_CHN + OUT_CHN * HIDN;
    k_prep_w<<<dim3((prep_total + 255) / 256), dim3(256), 0, stream>>>(W1, Ws, W2, Bt, W2t);
    k_rel<<<dim3(NR), dim3(512), 0, stream>>>(rel, W1, b1, Rb);
    if (use_xb) {
        long t8 = (long)N * IN_CHN / 8;
        k_prep_x<<<dim3((int)((t8 + 255) / 256)), dim3(256), 0, stream>>>(x, xb, t8);
        k_node<true><<<dim3((N + 63) / 64, 3), dim3(256), 0, stream>>>(x, xb, Bt, bs, X1, outp, N);
    } else {
        k_node<false><<<dim3((N + 63) / 64, 3), dim3(256), 0, stream>>>(x, xb, Bt, bs, X1, outp, N);
    }
    k_hist<<<dim3((E + 255) / 256), dim3(256), 0, stream>>>(ei, cnt, E);
    int NB = (N + 511) / 512;
    k_scan1<<<dim3(NB), dim3(512), 0, stream>>>(cnt, offs, bsum, N);
    k_scan2<<<dim3(1), dim3(512), 0, stream>>>(bsum, NB);
    k_scan3<<<dim3((N + 255) / 256), dim3(256), 0, stream>>>(offs, bsum, cnt, N, E);
    k_scatter<<<dim3((E + 255) / 256), dim3(256), 0, stream>>>(ei, etype, cnt, eperm, E);
    k_agg<<<dim3((N + 63) / 64), dim3(256), 0, stream>>>(offs, eperm, X1, Rb, W2t, b2, gamma, beta, outp, N);
}

// Round 3
// 559.263 us; speedup vs baseline: 1.2817x; 1.0958x over previous
//
#include <hip/hip_runtime.h>
#include <hip/hip_bf16.h>

#define IN_CHN 256
#define OUT_CHN 256
#define REL_DIM 1536
#define HIDN 512

using short8 = __attribute__((ext_vector_type(8))) short;
using f32x4  = __attribute__((ext_vector_type(4))) float;

__device__ __forceinline__ float bf2f(short s) {
    union { unsigned u; float f; } v;
    v.u = ((unsigned)(unsigned short)s) << 16;
    return v.f;
}
__device__ __forceinline__ unsigned cvt_pk_bf16(float a, float b) {
    unsigned r;
    asm("v_cvt_pk_bf16_f32 %0, %1, %2" : "=v"(r) : "v"(a), "v"(b));
    return r;
}
__device__ __forceinline__ unsigned short f2bf_s(float f) {
    union { float f; unsigned u; } v; v.f = f;
    unsigned u = v.u + 0x7FFFu + ((v.u >> 16) & 1u);
    return (unsigned short)(u >> 16);
}

// ---------------- prep: transpose+cast weights to bf16 ----------------
// Bt [512][256] = W1_top^T ; W2t[256][512] = W2^T ; Wst[256][256] = Ws^T
__global__ void k_prep_w(const float* __restrict__ W1, const float* __restrict__ Ws,
                         const float* __restrict__ W2,
                         unsigned short* __restrict__ Bt, unsigned short* __restrict__ W2t,
                         unsigned short* __restrict__ Wst)
{
    int idx = blockIdx.x * 256 + threadIdx.x;
    const int n1 = HIDN * IN_CHN;       // 131072
    const int n2 = OUT_CHN * HIDN;      // 131072
    const int n3 = OUT_CHN * IN_CHN;    // 65536
    if (idx < n1) {
        int j = idx >> 8, k = idx & 255;
        Bt[idx] = f2bf_s(W1[(size_t)k * HIDN + j]);
    } else if (idx < n1 + n2) {
        int t = idx - n1;
        int j = t >> 9, k = t & 511;
        W2t[t] = f2bf_s(W2[(size_t)k * OUT_CHN + j]);
    } else if (idx < n1 + n2 + n3) {
        int t = idx - n1 - n2;
        int j = t >> 8, k = t & 255;
        Wst[t] = f2bf_s(Ws[(size_t)k * OUT_CHN + j]);
    }
}

// ---------------- R[r] = rel[r] @ W1_bot + b1 (bf16 out) ----------------
__global__ __launch_bounds__(512) void k_rel(const float* __restrict__ rel,
                                             const float* __restrict__ W1,
                                             const float* __restrict__ b1,
                                             unsigned short* __restrict__ Rb)
{
    __shared__ float s[REL_DIM];
    const int r = blockIdx.x;
    for (int i = threadIdx.x; i < REL_DIM; i += 512)
        s[i] = rel[(size_t)r * REL_DIM + i];
    __syncthreads();
    const int j = threadIdx.x;
    float acc = b1[j];
    const float* wp = W1 + (size_t)IN_CHN * HIDN + j;
#pragma unroll 8
    for (int k = 0; k < REL_DIM; ++k)
        acc = fmaf(s[k], wp[(size_t)k * HIDN], acc);
    Rb[r * HIDN + j] = f2bf_s(acc);
}

// ---------------- node GEMM: X1 = bf16(x) @ Bt^T  (single pass, 512 thr) ----------------
// grid ceil(N/64); block 512 (8 waves). Block = 64 rows x 512 cols, K=256.
__global__ __launch_bounds__(512) void k_node(const float* __restrict__ x,
                                              const unsigned short* __restrict__ Bt,
                                              unsigned short* __restrict__ X1, int N)
{
    const int row0 = blockIdx.x * 64;
    const int tid = threadIdx.x;
    const int w = tid >> 6, l = tid & 63;
    const int l15 = l & 15, lg = l >> 4;
    const int colw = w * 64;

    const float* ap[4];
#pragma unroll
    for (int rf = 0; rf < 4; ++rf) {
        int row = row0 + 16 * rf + l15;
        if (row >= N) row = N - 1;
        ap[rf] = x + (size_t)row * IN_CHN + 8 * lg;
    }
    const unsigned short* bp[4];
#pragma unroll
    for (int cf = 0; cf < 4; ++cf)
        bp[cf] = Bt + (size_t)(colw + 16 * cf + l15) * IN_CHN + 8 * lg;

    f32x4 acc[4][4] = {};
    for (int k0 = 0; k0 < IN_CHN; k0 += 32) {
        short8 a[4], b[4];
#pragma unroll
        for (int rf = 0; rf < 4; ++rf) {
            float4 lo = *(const float4*)(ap[rf] + k0);
            float4 hi = *(const float4*)(ap[rf] + k0 + 4);
            union { short8 s; unsigned u[4]; } pk;
            pk.u[0] = cvt_pk_bf16(lo.x, lo.y);
            pk.u[1] = cvt_pk_bf16(lo.z, lo.w);
            pk.u[2] = cvt_pk_bf16(hi.x, hi.y);
            pk.u[3] = cvt_pk_bf16(hi.z, hi.w);
            a[rf] = pk.s;
        }
#pragma unroll
        for (int cf = 0; cf < 4; ++cf)
            b[cf] = *(const short8*)(bp[cf] + k0);
#pragma unroll
        for (int rf = 0; rf < 4; ++rf)
#pragma unroll
            for (int cf = 0; cf < 4; ++cf)
                acc[rf][cf] = __builtin_amdgcn_mfma_f32_16x16x32_bf16(a[rf], b[cf], acc[rf][cf], 0, 0, 0);
    }
#pragma unroll
    for (int rf = 0; rf < 4; ++rf) {
#pragma unroll
        for (int cf = 0; cf < 4; ++cf) {
            int col = colw + 16 * cf + l15;
#pragma unroll
            for (int r = 0; r < 4; ++r) {
                int row = row0 + 16 * rf + 4 * lg + r;
                if (row >= N) continue;
                X1[(size_t)row * HIDN + col] = f2bf_s(acc[rf][cf][r]);
            }
        }
    }
}

// ---------------- CSR build ----------------
__global__ void k_hist(const int* __restrict__ ei, int* __restrict__ cnt, int E)
{
    int e = blockIdx.x * 256 + threadIdx.x;
    if (e < E) atomicAdd(&cnt[ei[E + e]], 1);
}

__global__ __launch_bounds__(512) void k_scan1(const int* __restrict__ cnt, int* __restrict__ offs,
                                               int* __restrict__ bsum, int N)
{
    __shared__ int s[512];
    int t = threadIdx.x;
    int i = blockIdx.x * 512 + t;
    int v = (i < N) ? cnt[i] : 0;
    s[t] = v;
    __syncthreads();
    for (int d = 1; d < 512; d <<= 1) {
        int a = (t >= d) ? s[t - d] : 0;
        __syncthreads();
        s[t] += a;
        __syncthreads();
    }
    if (i < N) offs[i] = s[t] - v;
    if (t == 511) bsum[blockIdx.x] = s[511];
}

__global__ __launch_bounds__(512) void k_scan2(int* __restrict__ bsum, int NB)
{
    __shared__ int s[512];
    int t = threadIdx.x;
    if (t < NB) s[t] = bsum[t];
    __syncthreads();
    if (t == 0) {
        int run = 0;
        for (int j = 0; j < NB; ++j) { int v = s[j]; s[j] = run; run += v; }
    }
    __syncthreads();
    if (t < NB) bsum[t] = s[t];
}

__global__ void k_scan3(int* __restrict__ offs, const int* __restrict__ bsum,
                        int* __restrict__ cursor, int N, int E)
{
    int i = blockIdx.x * 256 + threadIdx.x;
    if (i < N) {
        int v = offs[i] + bsum[i >> 9];
        offs[i] = v;
        cursor[i] = v;
    }
    if (i == 0) offs[N] = E;
}

__global__ void k_scatter(const int* __restrict__ ei, const int* __restrict__ et,
                          int* __restrict__ cursor, int* __restrict__ eperm, int E)
{
    int e = blockIdx.x * 256 + threadIdx.x;
    if (e < E) {
        int d = ei[E + e];
        int pos = atomicAdd(&cursor[d], 1);
        eperm[pos] = ei[e] | (et[e] << 20);   // src | etype<<20
    }
}

// ---------------- fused: gather-agg H -> LDS, GEMM @W2 (K=512) + x@Ws (K=256), +deg*b2+bs, LN, ReLU ----------------
// grid ceil(N/32); block 256 (4 waves). 32 node rows x 256 out cols. LDS ~33 KB -> 4 blocks/CU.
__global__ __launch_bounds__(256) void k_agg(const int* __restrict__ offs,
                                             const int* __restrict__ eperm,
                                             const unsigned short* __restrict__ X1,
                                             const unsigned short* __restrict__ Rb,
                                             const unsigned short* __restrict__ W2t,
                                             const unsigned short* __restrict__ Wst,
                                             const float* __restrict__ x,
                                             const float* __restrict__ b2,
                                             const float* __restrict__ bs,
                                             const float* __restrict__ gamma,
                                             const float* __restrict__ beta,
                                             float* __restrict__ out, int N)
{
    __shared__ unsigned short shH[32 * HIDN];   // XOR-swizzled: elem block (l) ^ (n&7)
    __shared__ float sred[4][32], sqred[4][32];
    __shared__ int sdeg[32];
    const int tid = threadIdx.x;
    const int w = tid >> 6, l = tid & 63;
    const int l15 = l & 15, lg = l >> 4;
    const int row0 = blockIdx.x * 32;

    // ---- phase 1: aggregate relu(X1[src]+R[et]) over in-edges, 2-wide pipelined ----
    for (int i = 0; i < 8; ++i) {
        int n = w * 8 + i;
        int g = row0 + n;
        int o0 = 0, o1 = 0;
        if (g < N) { o0 = offs[g]; o1 = offs[g + 1]; }
        if (l == 0) sdeg[n] = o1 - o0;
        float a8[8] = {0.f, 0.f, 0.f, 0.f, 0.f, 0.f, 0.f, 0.f};
        int o = o0;
        for (; o + 2 <= o1; o += 2) {
            int p0 = eperm[o], p1 = eperm[o + 1];
            short8 x0 = *(const short8*)(X1 + (size_t)(p0 & 0xFFFFF) * HIDN + l * 8);
            short8 r0 = *(const short8*)(Rb + (p0 >> 20) * HIDN + l * 8);
            short8 x1 = *(const short8*)(X1 + (size_t)(p1 & 0xFFFFF) * HIDN + l * 8);
            short8 r1 = *(const short8*)(Rb + (p1 >> 20) * HIDN + l * 8);
#pragma unroll
            for (int j = 0; j < 8; ++j)
                a8[j] += fmaxf(bf2f(x0[j]) + bf2f(r0[j]), 0.f)
                       + fmaxf(bf2f(x1[j]) + bf2f(r1[j]), 0.f);
        }
        if (o < o1) {
            int p0 = eperm[o];
            short8 x0 = *(const short8*)(X1 + (size_t)(p0 & 0xFFFFF) * HIDN + l * 8);
            short8 r0 = *(const short8*)(Rb + (p0 >> 20) * HIDN + l * 8);
#pragma unroll
            for (int j = 0; j < 8; ++j)
                a8[j] += fmaxf(bf2f(x0[j]) + bf2f(r0[j]), 0.f);
        }
        union { short8 s; unsigned u[4]; } pkk;
        pkk.u[0] = cvt_pk_bf16(a8[0], a8[1]);
        pkk.u[1] = cvt_pk_bf16(a8[2], a8[3]);
        pkk.u[2] = cvt_pk_bf16(a8[4], a8[5]);
        pkk.u[3] = cvt_pk_bf16(a8[6], a8[7]);
        *(short8*)(shH + n * HIDN + ((l * 8) ^ ((n & 7) << 3))) = pkk.s;
    }
    __syncthreads();

    // ---- phase 2a: H @ W2t, K=512, A from LDS ----
    const int colw = w * 64;
    const unsigned short* bp[4];
#pragma unroll
    for (int cf = 0; cf < 4; ++cf)
        bp[cf] = W2t + (size_t)(colw + 16 * cf + l15) * HIDN + 8 * lg;
    int arow[2], axor[2];
#pragma unroll
    for (int rf = 0; rf < 2; ++rf) {
        int rr = 16 * rf + l15;
        arow[rf] = rr * HIDN;
        axor[rf] = (rr & 7) << 3;
    }
    f32x4 acc[2][4] = {};
    for (int k0 = 0; k0 < HIDN; k0 += 32) {
        short8 a[2], b[4];
#pragma unroll
        for (int rf = 0; rf < 2; ++rf)
            a[rf] = *(const short8*)(shH + arow[rf] + ((k0 + 8 * lg) ^ axor[rf]));
#pragma unroll
        for (int cf = 0; cf < 4; ++cf)
            b[cf] = *(const short8*)(bp[cf] + k0);
#pragma unroll
        for (int rf = 0; rf < 2; ++rf)
#pragma unroll
            for (int cf = 0; cf < 4; ++cf)
                acc[rf][cf] = __builtin_amdgcn_mfma_f32_16x16x32_bf16(a[rf], b[cf], acc[rf][cf], 0, 0, 0);
    }

    // ---- phase 2b: + x @ Wst, K=256, A direct from global (rows contiguous) ----
    const float* xp[2];
#pragma unroll
    for (int rf = 0; rf < 2; ++rf) {
        int row = row0 + 16 * rf + l15;
        if (row >= N) row = N - 1;
        xp[rf] = x + (size_t)row * IN_CHN + 8 * lg;
    }
    const unsigned short* sp[4];
#pragma unroll
    for (int cf = 0; cf < 4; ++cf)
        sp[cf] = Wst + (size_t)(colw + 16 * cf + l15) * IN_CHN + 8 * lg;
    for (int k0 = 0; k0 < IN_CHN; k0 += 32) {
        short8 a[2], b[4];
#pragma unroll
        for (int rf = 0; rf < 2; ++rf) {
            float4 lo = *(const float4*)(xp[rf] + k0);
            float4 hi = *(const float4*)(xp[rf] + k0 + 4);
            union { short8 s; unsigned u[4]; } pk;
            pk.u[0] = cvt_pk_bf16(lo.x, lo.y);
            pk.u[1] = cvt_pk_bf16(lo.z, lo.w);
            pk.u[2] = cvt_pk_bf16(hi.x, hi.y);
            pk.u[3] = cvt_pk_bf16(hi.z, hi.w);
            a[rf] = pk.s;
        }
#pragma unroll
        for (int cf = 0; cf < 4; ++cf)
            b[cf] = *(const short8*)(sp[cf] + k0);
#pragma unroll
        for (int rf = 0; rf < 2; ++rf)
#pragma unroll
            for (int cf = 0; cf < 4; ++cf)
                acc[rf][cf] = __builtin_amdgcn_mfma_f32_16x16x32_bf16(a[rf], b[cf], acc[rf][cf], 0, 0, 0);
    }

    // ---- epilogue: + deg*b2 + bs, LayerNorm over 256 cols, ReLU ----
    float b2v[4], bsv[4], gv[4], bv[4];
#pragma unroll
    for (int cf = 0; cf < 4; ++cf) {
        int col = colw + 16 * cf + l15;
        b2v[cf] = b2[col]; bsv[cf] = bs[col]; gv[cf] = gamma[col]; bv[cf] = beta[col];
    }
#pragma unroll
    for (int rf = 0; rf < 2; ++rf) {
#pragma unroll
        for (int r = 0; r < 4; ++r) {
            int row = 16 * rf + 4 * lg + r;
            float dg = (float)sdeg[row];
            float s = 0.f, sq = 0.f;
#pragma unroll
            for (int cf = 0; cf < 4; ++cf) {
                float v = acc[rf][cf][r] + dg * b2v[cf] + bsv[cf];
                acc[rf][cf][r] = v;
                s += v; sq += v * v;
            }
#pragma unroll
            for (int o = 8; o > 0; o >>= 1) {
                s  += __shfl_xor(s, o);
                sq += __shfl_xor(sq, o);
            }
            if (l15 == 0) { sred[w][row] = s; sqred[w][row] = sq; }
        }
    }
    __syncthreads();
#pragma unroll
    for (int rf = 0; rf < 2; ++rf) {
#pragma unroll
        for (int r = 0; r < 4; ++r) {
            int row = 16 * rf + 4 * lg + r;
            int g = row0 + row;
            if (g >= N) continue;
            float tot  = sred[0][row] + sred[1][row] + sred[2][row] + sred[3][row];
            float totq = sqred[0][row] + sqred[1][row] + sqred[2][row] + sqred[3][row];
            float mu = tot * (1.f / OUT_CHN);
            float var = totq * (1.f / OUT_CHN) - mu * mu;
            float rstd = rsqrtf(var + 1e-5f);
#pragma unroll
            for (int cf = 0; cf < 4; ++cf) {
                int col = colw + 16 * cf + l15;
                float v = (acc[rf][cf][r] - mu) * rstd * gv[cf] + bv[cf];
                out[(size_t)g * OUT_CHN + col] = fmaxf(v, 0.f);
            }
        }
    }
}

extern "C" void kernel_launch(void* const* d_in, const int* in_sizes, int n_in,
                              void* d_out, int out_size, void* d_ws, size_t ws_size,
                              hipStream_t stream)
{
    const float* x     = (const float*)d_in[0];
    const int*   ei    = (const int*)d_in[1];
    const int*   etype = (const int*)d_in[2];
    const float* rel   = (const float*)d_in[3];
    const float* W1    = (const float*)d_in[4];
    const float* b1    = (const float*)d_in[5];
    const float* W2    = (const float*)d_in[6];
    const float* b2    = (const float*)d_in[7];
    const float* Ws    = (const float*)d_in[8];
    const float* bs    = (const float*)d_in[9];
    const float* gamma = (const float*)d_in[10];
    const float* beta  = (const float*)d_in[11];

    const int N  = in_sizes[0] / IN_CHN;
    const int E  = in_sizes[2];
    const int NR = in_sizes[3] / REL_DIM;
    float* outp = (float*)d_out;

    char* wsp = (char*)d_ws;
    auto carve = [&](size_t bytes) { char* p = wsp; wsp += (bytes + 255) & ~(size_t)255; return p; };
    unsigned short* X1  = (unsigned short*)carve((size_t)N * HIDN * 2);
    unsigned short* Rb  = (unsigned short*)carve((size_t)NR * HIDN * 2);
    unsigned short* Bt  = (unsigned short*)carve((size_t)HIDN * IN_CHN * 2);
    unsigned short* W2t = (unsigned short*)carve((size_t)OUT_CHN * HIDN * 2);
    unsigned short* Wst = (unsigned short*)carve((size_t)OUT_CHN * IN_CHN * 2);
    int* offs  = (int*)carve(((size_t)N + 1) * 4);
    int* cnt   = (int*)carve((size_t)N * 4);        // doubles as scatter cursor
    int* bsum  = (int*)carve(512 * 4);
    int* eperm = (int*)carve((size_t)E * 4);

    hipMemsetAsync(cnt, 0, (size_t)N * 4, stream);

    const int prep_total = HIDN * IN_CHN + OUT_CHN * HIDN + OUT_CHN * IN_CHN;
    k_prep_w<<<dim3((prep_total + 255) / 256), dim3(256), 0, stream>>>(W1, Ws, W2, Bt, W2t, Wst);
    k_rel<<<dim3(NR), dim3(512), 0, stream>>>(rel, W1, b1, Rb);
    k_node<<<dim3((N + 63) / 64), dim3(512), 0, stream>>>(x, Bt, X1, N);
    k_hist<<<dim3((E + 255) / 256), dim3(256), 0, stream>>>(ei, cnt, E);
    int NB = (N + 511) / 512;
    k_scan1<<<dim3(NB), dim3(512), 0, stream>>>(cnt, offs, bsum, N);
    k_scan2<<<dim3(1), dim3(512), 0, stream>>>(bsum, NB);
    k_scan3<<<dim3((N + 255) / 256), dim3(256), 0, stream>>>(offs, bsum, cnt, N, E);
    k_scatter<<<dim3((E + 255) / 256), dim3(256), 0, stream>>>(ei, etype, cnt, eperm, E);
    k_agg<<<dim3((N + 31) / 32), dim3(256), 0, stream>>>(offs, eperm, X1, Rb, W2t, Wst, x,
                                                         b2, bs, gamma, beta, outp, N);
}